// Round 17
// baseline (110.238 us; speedup 1.0000x reference)
//
#include <hip/hip_runtime.h>
#include <hip/hip_bf16.h>
#include <stdint.h>

#define N_NODES 100000
#define N_EDGES 1600000
#define CH 64

#define NPB 128                              // nodes per bucket (tgt >> 7)
#define NBUCK ((N_NODES + NPB - 1) / NPB)    // 782
#define CHUNK 4096                           // edges per bin/hist block
#define BT 1024                              // threads per bin/hist block
#define EPT (CHUNK / BT)                     // 4 edges per thread
#define NBLK_E ((N_EDGES + CHUNK - 1) / CHUNK)  // 391

#define STRIDE 2560  // fixed recs slots per bucket (mean 2046, sd ~45: 11 sigma)
#define CAP 3072     // tier-B sorter stash
#define ST 512       // sortb threads

#define GM 64   // nodes per rowgemm tile (tier C/D)
#define FN 64   // nodes per fused block (16 waves x 4 nodes)

typedef float f32x4 __attribute__((ext_vector_type(4)));

__device__ __forceinline__ unsigned short bf16rn(float f) {
  unsigned u = __float_as_uint(f);
  unsigned r = u + 0x7FFFu + ((u >> 16) & 1u);
  return (unsigned short)(r >> 16);
}

// ================= tier A: fixed-stride buckets (no hist, no scan) ==========

// bin2: single-pass scatter into fixed-stride bucket regions + fused x->bf16.
__global__ __launch_bounds__(BT) void bin2_kernel(const int* __restrict__ ei,
                                                  const float* __restrict__ attr,
                                                  const float* __restrict__ gp,
                                                  int* __restrict__ gcur,
                                                  uint2* __restrict__ recs,
                                                  const float* __restrict__ x,
                                                  unsigned short* __restrict__ xh) {
  __shared__ int lhist[NBUCK];
  __shared__ int lbase[NBUCK];
  const int tid = threadIdx.x;
  for (int i = tid; i < NBUCK; i += BT) lhist[i] = 0;
  __syncthreads();
  const int cbase = blockIdx.x * CHUNK;
  const float inv = 1.0f / (gp[0] * gp[0] + 1e-8f);

  int s[EPT], t[EPT], lrank[EPT];
  float g[EPT];
#pragma unroll
  for (int k = 0; k < EPT; ++k) {
    const int e = cbase + k * BT + tid;
    if (e < N_EDGES) {
      s[k] = ei[e];
      t[k] = ei[N_EDGES + e];
      const float d = attr[3 * e];
      g[k] = __expf(-d * d * inv);
      lrank[k] = atomicAdd(&lhist[t[k] >> 7], 1);
    }
  }
  // fused bf16 conversion (independent streaming work, grid-stride)
  {
    const int nq = N_NODES * CH / 4;
    const int stride = gridDim.x * BT;
    for (int q = blockIdx.x * BT + tid; q < nq; q += stride) {
      const float4 v = reinterpret_cast<const float4*>(x)[q];
      ushort4 o;
      o.x = bf16rn(v.x);
      o.y = bf16rn(v.y);
      o.z = bf16rn(v.z);
      o.w = bf16rn(v.w);
      reinterpret_cast<ushort4*>(xh)[q] = o;
    }
  }
  __syncthreads();
  for (int i = tid; i < NBUCK; i += BT) {
    const int c = lhist[i];
    if (c) lbase[i] = i * STRIDE + atomicAdd(&gcur[i], c);
  }
  __syncthreads();

#pragma unroll
  for (int k = 0; k < EPT; ++k) {
    const int e = cbase + k * BT + tid;
    if (e < N_EDGES) {
      const int bb = t[k] >> 7;
      const int idx = lbase[bb] + lrank[k];
      if (idx < (bb + 1) * STRIDE) {  // overflow guard (11-sigma margin)
        uint2 rec;
        rec.x = (unsigned)s[k] | ((unsigned)(t[k] & (NPB - 1)) << 17);
        rec.y = __float_as_uint(g[k]);
        recs[idx] = rec;
      }
    }
  }
}

// sortb2: counting sort within each fixed-stride bucket; emits offs + ends.
__global__ __launch_bounds__(ST) void sortb2_kernel(const int* __restrict__ gcur,
                                                    uint2* __restrict__ recs,
                                                    int* __restrict__ offs,
                                                    int* __restrict__ ends) {
  __shared__ uint2 srec[STRIDE];  // 20 KB
  __shared__ int lhist[NPB];
  __shared__ int lofs[NPB];
  __shared__ int lcur[NPB];
  const int b = blockIdx.x;
  const int tid = threadIdx.x;
  const int start = b * STRIDE;
  int cnt = gcur[b];
  cnt = cnt < STRIDE ? cnt : STRIDE;

  if (tid < NPB) lhist[tid] = 0;
  __syncthreads();
  for (int i = tid; i < cnt; i += ST) {
    const uint2 r = recs[start + i];
    srec[i] = r;
    atomicAdd(&lhist[r.x >> 17], 1);
  }
  __syncthreads();
  if (tid < NPB) lofs[tid] = lhist[tid];
  __syncthreads();
  for (int off = 1; off < NPB; off <<= 1) {
    int t = 0;
    if (tid < NPB && tid >= off) t = lofs[tid - off];
    __syncthreads();
    if (tid < NPB) lofs[tid] += t;
    __syncthreads();
  }
  if (tid < NPB) {
    const int incl = lofs[tid];
    const int excl = incl - lhist[tid];
    lcur[tid] = excl;
    const int node = b * NPB + tid;
    if (node < N_NODES) {
      offs[node] = start + excl;
      ends[node] = start + incl;
    }
  }
  __syncthreads();
  for (int i = tid; i < cnt; i += ST) {
    const uint2 r = srec[i];
    const int pos = atomicAdd(&lcur[r.x >> 17], 1);
    recs[start + pos] = r;
  }
}

// ================= tier B support: exact-offset pipeline ====================

__global__ __launch_bounds__(BT) void hist2_kernel(const int* __restrict__ ei,
                                                   int* __restrict__ ghist,
                                                   const float* __restrict__ x,
                                                   unsigned short* __restrict__ xh,
                                                   int do_conv) {
  __shared__ int lh[NBUCK];
  const int tid = threadIdx.x;
  for (int i = tid; i < NBUCK; i += BT) lh[i] = 0;
  __syncthreads();
  const int cbase = blockIdx.x * CHUNK;
#pragma unroll
  for (int k = 0; k < EPT; ++k) {
    const int e = cbase + k * BT + tid;
    if (e < N_EDGES) atomicAdd(&lh[ei[N_EDGES + e] >> 7], 1);
  }
  if (do_conv) {
    const int nq = N_NODES * CH / 4;
    const int stride = gridDim.x * BT;
    for (int q = blockIdx.x * BT + tid; q < nq; q += stride) {
      const float4 v = reinterpret_cast<const float4*>(x)[q];
      ushort4 o;
      o.x = bf16rn(v.x);
      o.y = bf16rn(v.y);
      o.z = bf16rn(v.z);
      o.w = bf16rn(v.w);
      reinterpret_cast<ushort4*>(xh)[q] = o;
    }
  }
  __syncthreads();
  for (int i = tid; i < NBUCK; i += BT) {
    const int c = lh[i];
    if (c) atomicAdd(&ghist[i], c);
  }
}

__global__ __launch_bounds__(1024) void scan_kernel(const int* __restrict__ ghist,
                                                    int* __restrict__ gbase,
                                                    int* __restrict__ gcur) {
  __shared__ int sd[1024];
  const int tid = threadIdx.x;
  const int v = (tid < NBUCK) ? ghist[tid] : 0;
  sd[tid] = v;
  __syncthreads();
  for (int off = 1; off < 1024; off <<= 1) {
    int t = (tid >= off) ? sd[tid - off] : 0;
    __syncthreads();
    sd[tid] += t;
    __syncthreads();
  }
  if (tid < NBUCK) {
    const int excl = sd[tid] - v;
    gbase[tid] = excl;
    gcur[tid] = excl;
  }
}

__global__ __launch_bounds__(BT) void bin_kernel(const int* __restrict__ ei,
                                                 const float* __restrict__ attr,
                                                 const float* __restrict__ gp,
                                                 int* __restrict__ gcur,
                                                 uint2* __restrict__ recs) {
  __shared__ int lhist[NBUCK];
  __shared__ int lbase[NBUCK];
  const int tid = threadIdx.x;
  for (int i = tid; i < NBUCK; i += BT) lhist[i] = 0;
  __syncthreads();
  const int cbase = blockIdx.x * CHUNK;
  const float inv = 1.0f / (gp[0] * gp[0] + 1e-8f);

  int s[EPT], t[EPT], lrank[EPT];
  float g[EPT];
#pragma unroll
  for (int k = 0; k < EPT; ++k) {
    const int e = cbase + k * BT + tid;
    if (e < N_EDGES) {
      s[k] = ei[e];
      t[k] = ei[N_EDGES + e];
      const float d = attr[3 * e];
      g[k] = __expf(-d * d * inv);
      lrank[k] = atomicAdd(&lhist[t[k] >> 7], 1);
    }
  }
  __syncthreads();
  for (int i = tid; i < NBUCK; i += BT) {
    const int c = lhist[i];
    if (c) lbase[i] = atomicAdd(&gcur[i], c);
  }
  __syncthreads();

#pragma unroll
  for (int k = 0; k < EPT; ++k) {
    const int e = cbase + k * BT + tid;
    if (e < N_EDGES) {
      uint2 rec;
      rec.x = (unsigned)s[k] | ((unsigned)(t[k] & (NPB - 1)) << 17);
      rec.y = __float_as_uint(g[k]);
      recs[lbase[t[k] >> 7] + lrank[k]] = rec;
    }
  }
}

__global__ __launch_bounds__(ST) void sortb_kernel(const int* __restrict__ gbase,
                                                   const int* __restrict__ ghist,
                                                   uint2* __restrict__ recs,
                                                   int* __restrict__ offs) {
  __shared__ uint2 srec[CAP];  // 24 KB
  __shared__ int lhist[NPB];
  __shared__ int lofs[NPB];
  __shared__ int lcur[NPB];
  const int b = blockIdx.x;
  const int tid = threadIdx.x;
  const int start = gbase[b];
  const int cnt = ghist[b] < CAP ? ghist[b] : CAP;

  if (tid < NPB) lhist[tid] = 0;
  __syncthreads();
  for (int i = tid; i < cnt; i += ST) {
    const uint2 r = recs[start + i];
    srec[i] = r;
    atomicAdd(&lhist[r.x >> 17], 1);
  }
  __syncthreads();
  if (tid < NPB) lofs[tid] = lhist[tid];
  __syncthreads();
  for (int off = 1; off < NPB; off <<= 1) {
    int t = 0;
    if (tid < NPB && tid >= off) t = lofs[tid - off];
    __syncthreads();
    if (tid < NPB) lofs[tid] += t;
    __syncthreads();
  }
  if (tid < NPB) {
    const int excl = lofs[tid] - lhist[tid];
    lcur[tid] = excl;
    const int node = b * NPB + tid;
    if (node < N_NODES) offs[node] = start + excl;
  }
  if (b == NBUCK - 1 && tid == 0) offs[N_NODES] = start + cnt;
  __syncthreads();
  for (int i = tid; i < cnt; i += ST) {
    const uint2 r = srec[i];
    const int pos = atomicAdd(&lcur[r.x >> 17], 1);
    recs[start + pos] = r;
  }
}

// ============== fused gather + GEMM (tiers A/B) =============================
// 1024 threads = 16 waves; wave owns 4 nodes. Gather writes s directly into a
// wave-private column slab of the transposed LDS tile sT[k][4w..4w+3]; GEMM
// reads sT[k][4w] as a same-address b128 broadcast (conflict-free) and
// wl[k*64+lane] stride-1. No barriers after W staging (data is wave-private).
__global__ __launch_bounds__(1024) void fusedrg_kernel(
    const float* __restrict__ x, const unsigned short* __restrict__ xh,
    const int* __restrict__ offs, const int* __restrict__ ends,
    const uint2* __restrict__ recs, const float* __restrict__ W,
    const float* __restrict__ bias, float* __restrict__ out) {
  __shared__ float sT[CH][68];   // s transposed, 17408 B
  __shared__ float wl[CH * CH];  // 16384 B
  __shared__ float bl[CH];
  const int tid = threadIdx.x;
  {
    const float4* W4 = reinterpret_cast<const float4*>(W);
    float4* wl4 = reinterpret_cast<float4*>(wl);
    wl4[tid] = W4[tid];  // 1024 x float4 = whole W
    if (tid < CH) bl[tid] = bias[tid];
  }
  __syncthreads();  // only barrier

  const int w = tid >> 6;  // wave 0..15
  const int lane = tid & 63;
  const int c2 = lane & 31;  // channel pair 2c2, 2c2+1
  const int eh = lane >> 5;  // which edge of a pair this half-wave takes
  const int node0 = blockIdx.x * FN;

  // phase 1: gather s for this wave's 4 nodes into sT cols 4w..4w+3
#pragma unroll 1
  for (int i = 0; i < 4; ++i) {
    const int node = node0 + 4 * w + i;
    if (node >= N_NODES) break;
    const int n0 = __builtin_amdgcn_readfirstlane(offs[node]);
    const int n1 = __builtin_amdgcn_readfirstlane(ends[node]);
    const int m = n1 - n0;

    float ax = 0.0f, ay = 0.0f;
    int j = 0;
    for (; j + 16 <= m; j += 16) {  // 8 pair-gathers in flight
#pragma unroll
      for (int p = 0; p < 8; ++p) {
        const uint2 r0 = recs[n0 + j + 2 * p];      // uniform -> s_load
        const uint2 r1 = recs[n0 + j + 2 * p + 1];
        const unsigned sx = (eh ? r1.x : r0.x) & 0x1FFFFu;
        const float g = __uint_as_float(eh ? r1.y : r0.y);
        const unsigned u =
            *reinterpret_cast<const unsigned*>(&xh[(size_t)sx * CH + c2 * 2]);
        ax += g * __uint_as_float(u << 16);
        ay += g * __uint_as_float(u & 0xFFFF0000u);
      }
    }
    for (; j + 8 <= m; j += 8) {
#pragma unroll
      for (int p = 0; p < 4; ++p) {
        const uint2 r0 = recs[n0 + j + 2 * p];
        const uint2 r1 = recs[n0 + j + 2 * p + 1];
        const unsigned sx = (eh ? r1.x : r0.x) & 0x1FFFFu;
        const float g = __uint_as_float(eh ? r1.y : r0.y);
        const unsigned u =
            *reinterpret_cast<const unsigned*>(&xh[(size_t)sx * CH + c2 * 2]);
        ax += g * __uint_as_float(u << 16);
        ay += g * __uint_as_float(u & 0xFFFF0000u);
      }
    }
    for (; j < m; j += 2) {
      const uint2 r0 = recs[n0 + j];
      uint2 r1 = {0u, 0u};  // pad: s=0,g=0 -> harmless row-0 read
      if (j + 1 < m) r1 = recs[n0 + j + 1];
      const unsigned sx = (eh ? r1.x : r0.x) & 0x1FFFFu;
      const float g = __uint_as_float(eh ? r1.y : r0.y);
      const unsigned u =
          *reinterpret_cast<const unsigned*>(&xh[(size_t)sx * CH + c2 * 2]);
      ax += g * __uint_as_float(u << 16);
      ay += g * __uint_as_float(u & 0xFFFF0000u);
    }
    ax += __shfl_xor(ax, 32);
    ay += __shfl_xor(ay, 32);
    if (lane < 32) {
      const float2 xv =
          reinterpret_cast<const float2*>(x + (size_t)node * CH)[c2];
      sT[2 * c2][4 * w + i] = ax + xv.x;      // 8-way bank alias, 8 writes/node
      sT[2 * c2 + 1][4 * w + i] = ay + xv.y;  // -> negligible
    }
  }

  // phase 2: in-wave GEMM. lane = output channel; 4 nodes per wave.
  float a0 = 0.f, a1 = 0.f, a2 = 0.f, a3 = 0.f;
#pragma unroll 8
  for (int k = 0; k < CH; ++k) {
    const f32x4 sv = *reinterpret_cast<const f32x4*>(&sT[k][4 * w]);
    const float wv = wl[k * CH + lane];
    a0 += sv.x * wv;
    a1 += sv.y * wv;
    a2 += sv.z * wv;
    a3 += sv.w * wv;
  }
  const float bb = bl[lane];
  float accs[4] = {a0, a1, a2, a3};
#pragma unroll
  for (int i = 0; i < 4; ++i) {
    const int node = node0 + 4 * w + i;
    if (node < N_NODES) out[(size_t)node * CH + lane] = bb + accs[i];
  }
}

// ============== tier C/D support ============================================

// reduce3 (tier C): fp32 gathers via shfl broadcast; writes s = agg + x.
__global__ __launch_bounds__(256) void reduce3_kernel(
    const float* __restrict__ x, const int* __restrict__ offs,
    const uint2* __restrict__ recs, float* __restrict__ out) {
  const int node = (blockIdx.x * blockDim.x + threadIdx.x) >> 6;
  if (node >= N_NODES) return;
  const int lane = threadIdx.x & 63;
  const int n0 = offs[node];
  const int m = offs[node + 1] - n0;

  float acc = 0.0f;
  for (int base = 0; base < m; base += 64) {
    const int mm = (m - base) < 64 ? (m - base) : 64;
    uint2 pr = {0u, 0u};
    if (lane < mm) pr = recs[n0 + base + lane];
    const int pk_all = (int)pr.x;
    const float g_all = __uint_as_float(pr.y);
    int j = 0;
    for (; j + 4 <= mm; j += 4) {
      const int s0 = __shfl(pk_all, j + 0) & 0x1FFFF;
      const int s1 = __shfl(pk_all, j + 1) & 0x1FFFF;
      const int s2 = __shfl(pk_all, j + 2) & 0x1FFFF;
      const int s3 = __shfl(pk_all, j + 3) & 0x1FFFF;
      const float g0 = __shfl(g_all, j + 0);
      const float g1 = __shfl(g_all, j + 1);
      const float g2 = __shfl(g_all, j + 2);
      const float g3 = __shfl(g_all, j + 3);
      acc += g0 * x[(size_t)s0 * CH + lane] + g1 * x[(size_t)s1 * CH + lane] +
             g2 * x[(size_t)s2 * CH + lane] + g3 * x[(size_t)s3 * CH + lane];
    }
    for (; j < mm; ++j) {
      const int sj = __shfl(pk_all, j) & 0x1FFFF;
      const float gj = __shfl(g_all, j);
      acc += gj * x[(size_t)sj * CH + lane];
    }
  }
  out[(size_t)node * CH + lane] = acc + x[(size_t)node * CH + lane];
}

// fallback: atomic scatter
__global__ __launch_bounds__(256) void scatter_kernel(
    const float* __restrict__ x, const int* __restrict__ ei,
    const float* __restrict__ attr, const float* __restrict__ gp,
    float* __restrict__ agg) {
  const int lane = threadIdx.x & 63;
  const int wave = (blockIdx.x * blockDim.x + threadIdx.x) >> 6;
  const int nwaves = (gridDim.x * blockDim.x) >> 6;
  const float inv = 1.0f / (gp[0] * gp[0] + 1e-8f);
  for (int base = wave * 64; base < N_EDGES; base += nwaves * 64) {
    const int e = base + lane;
    const int s = ei[e];
    const int t = ei[N_EDGES + e];
    const float d = attr[3 * e];
    const float g = __expf(-d * d * inv);
#pragma unroll 1
    for (int j = 0; j < 64; ++j) {
      const int sj = __shfl(s, j);
      const int tj = __shfl(t, j);
      const float gj = __shfl(g, j);
      atomicAdd(&agg[(size_t)tj * CH + lane], gj * x[sj * CH + lane]);
    }
  }
}

// rowgemm3 (tier C): out = out @ W + bias (s already includes x).
__global__ __launch_bounds__(256) void rowgemm3_kernel(
    const float* __restrict__ W, const float* __restrict__ bias,
    float* __restrict__ out) {
  __shared__ float sT[64][GM + 4];
  __shared__ float wl[64 * 64];
  const int tid = threadIdx.x;
  const int node0 = blockIdx.x * GM;

  {
    const float4* W4 = reinterpret_cast<const float4*>(W);
    float4* wl4 = reinterpret_cast<float4*>(wl);
#pragma unroll
    for (int i = 0; i < 4; ++i) wl4[i * 256 + tid] = W4[i * 256 + tid];
  }
  {
    const int m = tid >> 2;
    const int kq = tid & 3;
    if (node0 + m < N_NODES) {
      const float4* r4 =
          reinterpret_cast<const float4*>(out + (size_t)(node0 + m) * CH);
#pragma unroll
      for (int q = 0; q < 4; ++q) {
        const float4 v = r4[kq * 4 + q];
        const int k = kq * 16 + q * 4;
        sT[k + 0][m] = v.x;
        sT[k + 1][m] = v.y;
        sT[k + 2][m] = v.z;
        sT[k + 3][m] = v.w;
      }
    }
  }
  __syncthreads();

  const int m0 = (tid >> 4) * 4;
  const int c0 = (tid & 15) * 4;

  const f32x4 b4 = *reinterpret_cast<const f32x4*>(&bias[c0]);
  f32x4 acc0 = b4, acc1 = b4, acc2 = b4, acc3 = b4;

#pragma unroll 8
  for (int k = 0; k < 64; ++k) {
    const f32x4 sv = *reinterpret_cast<const f32x4*>(&sT[k][m0]);
    const f32x4 wv = *reinterpret_cast<const f32x4*>(&wl[k * 64 + c0]);
    acc0 += sv.x * wv;
    acc1 += sv.y * wv;
    acc2 += sv.z * wv;
    acc3 += sv.w * wv;
  }

  __syncthreads();
  f32x4 accs[4] = {acc0, acc1, acc2, acc3};
#pragma unroll
  for (int i = 0; i < 4; ++i) {
    const int node = node0 + m0 + i;
    if (node < N_NODES)
      *reinterpret_cast<f32x4*>(&out[(size_t)node * CH + c0]) = accs[i];
  }
}

// rowgemm (tier D): out = (x + out) @ W + bias.
__global__ __launch_bounds__(256) void rowgemm_kernel(
    const float* __restrict__ x, const float* __restrict__ W,
    const float* __restrict__ bias, float* __restrict__ out) {
  const int r = blockIdx.x * blockDim.x + threadIdx.x;
  if (r >= N_NODES) return;
  const float* xr = x + (size_t)r * CH;
  float* outr = out + (size_t)r * CH;

  float s[CH];
#pragma unroll
  for (int k4 = 0; k4 < CH / 4; ++k4) {
    float4 xv = *reinterpret_cast<const float4*>(xr + k4 * 4);
    float4 av = *reinterpret_cast<const float4*>(outr + k4 * 4);
    s[k4 * 4 + 0] = xv.x + av.x;
    s[k4 * 4 + 1] = xv.y + av.y;
    s[k4 * 4 + 2] = xv.z + av.z;
    s[k4 * 4 + 3] = xv.w + av.w;
  }

  float acc[CH];
#pragma unroll
  for (int c = 0; c < CH; ++c) acc[c] = bias[c];

#pragma unroll
  for (int k = 0; k < CH; ++k) {
    const float sk = s[k];
#pragma unroll
    for (int c4 = 0; c4 < CH / 4; ++c4) {
      const float4 w = *reinterpret_cast<const float4*>(&W[k * CH + c4 * 4]);
      acc[c4 * 4 + 0] += sk * w.x;
      acc[c4 * 4 + 1] += sk * w.y;
      acc[c4 * 4 + 2] += sk * w.z;
      acc[c4 * 4 + 3] += sk * w.w;
    }
  }

#pragma unroll
  for (int c4 = 0; c4 < CH / 4; ++c4) {
    float4 o = {acc[c4 * 4 + 0], acc[c4 * 4 + 1], acc[c4 * 4 + 2],
                acc[c4 * 4 + 3]};
    *reinterpret_cast<float4*>(outr + c4 * 4) = o;
  }
}

// ---------- launch ----------
extern "C" void kernel_launch(void* const* d_in, const int* in_sizes, int n_in,
                              void* d_out, int out_size, void* d_ws,
                              size_t ws_size, hipStream_t stream) {
  const float* x = (const float*)d_in[0];
  const int* ei = (const int*)d_in[1];  // harness delivers int32
  const float* attr = (const float*)d_in[2];
  const float* W = (const float*)d_in[3];
  const float* bias = (const float*)d_in[4];
  const float* gp = (const float*)d_in[5];
  float* out = (float*)d_out;

  const size_t sz_i = ((size_t)NBUCK * 4 + 255) & ~(size_t)255;  // 3328
  const size_t sz_xh = (size_t)N_NODES * CH * 2;                 // 12.8 MB
  const size_t sz_offs1 = ((size_t)N_NODES * 4 + 255) & ~(size_t)255;

  // Tier A (fixed stride): gcur | recsA (782*2560*8) | offs | ends | xh
  const size_t sz_recsA = (size_t)NBUCK * STRIDE * 8;  // 16.0 MB
  const size_t need_fs = sz_i + sz_recsA + 2 * sz_offs1 + sz_xh;  // ~29.6 MB

  // Tier B/C (exact offsets): ghist|gbase|gcur | recs (12.8MB) | offs(N+1) | xh
  const size_t sz_recsB = (size_t)N_EDGES * 8;
  const size_t sz_offsB = ((size_t)(N_NODES + 1) * 4 + 255) & ~(size_t)255;
  const size_t need_b = 3 * sz_i + sz_recsB + sz_offsB;  // ~13.2 MB
  const size_t need_a = need_b + sz_xh;                  // ~26.0 MB

  if (ws_size >= need_fs) {
    char* base = (char*)d_ws;
    int* gcur = (int*)base;
    uint2* recs = (uint2*)(base + sz_i);
    int* offs = (int*)(base + sz_i + sz_recsA);
    int* ends = (int*)(base + sz_i + sz_recsA + sz_offs1);
    unsigned short* xh =
        (unsigned short*)(base + sz_i + sz_recsA + 2 * sz_offs1);

    hipMemsetAsync(gcur, 0, (size_t)NBUCK * 4, stream);
    bin2_kernel<<<NBLK_E, BT, 0, stream>>>(ei, attr, gp, gcur, recs, x, xh);
    sortb2_kernel<<<NBUCK, ST, 0, stream>>>(gcur, recs, offs, ends);
    fusedrg_kernel<<<(N_NODES + FN - 1) / FN, 1024, 0, stream>>>(
        x, xh, offs, ends, recs, W, bias, out);
  } else if (ws_size >= need_b) {
    char* base = (char*)d_ws;
    int* ghist = (int*)base;
    int* gbase = (int*)(base + sz_i);
    int* gcur = (int*)(base + 2 * sz_i);
    uint2* recs = (uint2*)(base + 3 * sz_i);
    int* offs = (int*)(base + 3 * sz_i + sz_recsB);
    unsigned short* xh = (unsigned short*)(base + need_b);

    const int tier_a = (ws_size >= need_a) ? 1 : 0;
    hipMemsetAsync(ghist, 0, (size_t)NBUCK * 4, stream);
    hist2_kernel<<<NBLK_E, BT, 0, stream>>>(ei, ghist, x, xh, tier_a);
    scan_kernel<<<1, 1024, 0, stream>>>(ghist, gbase, gcur);
    bin_kernel<<<NBLK_E, BT, 0, stream>>>(ei, attr, gp, gcur, recs);
    sortb_kernel<<<NBUCK, ST, 0, stream>>>(gbase, ghist, recs, offs);
    if (tier_a) {
      fusedrg_kernel<<<(N_NODES + FN - 1) / FN, 1024, 0, stream>>>(
          x, xh, offs, offs + 1, recs, W, bias, out);
    } else {
      reduce3_kernel<<<(N_NODES * 64 + 255) / 256, 256, 0, stream>>>(x, offs,
                                                                     recs, out);
      rowgemm3_kernel<<<(N_NODES + GM - 1) / GM, 256, 0, stream>>>(W, bias,
                                                                   out);
    }
  } else {
    hipMemsetAsync(out, 0, (size_t)N_NODES * CH * sizeof(float), stream);
    scatter_kernel<<<2048, 256, 0, stream>>>(x, ei, attr, gp, out);
    rowgemm_kernel<<<(N_NODES + 255) / 256, 256, 0, stream>>>(x, W, bias, out);
  }
}

// Round 18
// 104.447 us; speedup vs baseline: 1.0554x; 1.0554x over previous
//
#include <hip/hip_runtime.h>
#include <hip/hip_bf16.h>
#include <stdint.h>

#define N_NODES 100000
#define N_EDGES 1600000
#define CH 64

#define NPB 128                              // nodes per bucket (tgt >> 7)
#define NBUCK ((N_NODES + NPB - 1) / NPB)    // 782
#define CHUNK 4096                           // edges per bin/hist block
#define BT 1024                              // threads per bin/hist block
#define EPT (CHUNK / BT)                     // 4 edges per thread
#define NBLK_E ((N_EDGES + CHUNK - 1) / CHUNK)  // 391

#define STRIDE 2560  // fixed recs slots per bucket (mean 2046, sd ~45: 11 sigma)
#define CAP 3072     // tier-B sorter stash
#define ST 1024      // sortb threads (2046 recs in 2 strided iters)

#define GM 64  // nodes per rowgemm tile

typedef float f32x4 __attribute__((ext_vector_type(4)));

__device__ __forceinline__ unsigned short bf16rn(float f) {
  unsigned u = __float_as_uint(f);
  unsigned r = u + 0x7FFFu + ((u >> 16) & 1u);
  return (unsigned short)(r >> 16);
}

__device__ __forceinline__ float bf16f(unsigned short h) {
  return __uint_as_float((unsigned)h << 16);
}

// ================= tier A: fixed-stride buckets (no hist, no scan) ==========

// bin2: single-pass scatter into fixed-stride bucket regions + fused x->bf16.
__global__ __launch_bounds__(BT) void bin2_kernel(const int* __restrict__ ei,
                                                  const float* __restrict__ attr,
                                                  const float* __restrict__ gp,
                                                  int* __restrict__ gcur,
                                                  uint2* __restrict__ recs,
                                                  const float* __restrict__ x,
                                                  unsigned short* __restrict__ xh) {
  __shared__ int lhist[NBUCK];
  __shared__ int lbase[NBUCK];
  const int tid = threadIdx.x;
  for (int i = tid; i < NBUCK; i += BT) lhist[i] = 0;
  __syncthreads();
  const int cbase = blockIdx.x * CHUNK;
  const float inv = 1.0f / (gp[0] * gp[0] + 1e-8f);

  int s[EPT], t[EPT], lrank[EPT];
  float g[EPT];
#pragma unroll
  for (int k = 0; k < EPT; ++k) {
    const int e = cbase + k * BT + tid;
    if (e < N_EDGES) {
      s[k] = ei[e];
      t[k] = ei[N_EDGES + e];
      const float d = attr[3 * e];
      g[k] = __expf(-d * d * inv);
      lrank[k] = atomicAdd(&lhist[t[k] >> 7], 1);
    }
  }
  // fused bf16 conversion (independent streaming work, grid-stride)
  {
    const int nq = N_NODES * CH / 4;
    const int stride = gridDim.x * BT;
    for (int q = blockIdx.x * BT + tid; q < nq; q += stride) {
      const float4 v = reinterpret_cast<const float4*>(x)[q];
      ushort4 o;
      o.x = bf16rn(v.x);
      o.y = bf16rn(v.y);
      o.z = bf16rn(v.z);
      o.w = bf16rn(v.w);
      reinterpret_cast<ushort4*>(xh)[q] = o;
    }
  }
  __syncthreads();
  for (int i = tid; i < NBUCK; i += BT) {
    const int c = lhist[i];
    if (c) lbase[i] = i * STRIDE + atomicAdd(&gcur[i], c);
  }
  __syncthreads();

#pragma unroll
  for (int k = 0; k < EPT; ++k) {
    const int e = cbase + k * BT + tid;
    if (e < N_EDGES) {
      const int bb = t[k] >> 7;
      const int idx = lbase[bb] + lrank[k];
      if (idx < (bb + 1) * STRIDE) {  // overflow guard (11-sigma margin)
        uint2 rec;
        rec.x = (unsigned)s[k] | ((unsigned)(t[k] & (NPB - 1)) << 17);
        rec.y = __float_as_uint(g[k]);
        recs[idx] = rec;
      }
    }
  }
}

// sortb2: counting sort within each fixed-stride bucket; emits offs + ends.
__global__ __launch_bounds__(ST) void sortb2_kernel(const int* __restrict__ gcur,
                                                    uint2* __restrict__ recs,
                                                    int* __restrict__ offs,
                                                    int* __restrict__ ends) {
  __shared__ uint2 srec[STRIDE];  // 20 KB
  __shared__ int lhist[NPB];
  __shared__ int lofs[NPB];
  __shared__ int lcur[NPB];
  const int b = blockIdx.x;
  const int tid = threadIdx.x;
  const int start = b * STRIDE;
  int cnt = gcur[b];
  cnt = cnt < STRIDE ? cnt : STRIDE;

  if (tid < NPB) lhist[tid] = 0;
  __syncthreads();
  for (int i = tid; i < cnt; i += ST) {
    const uint2 r = recs[start + i];
    srec[i] = r;
    atomicAdd(&lhist[r.x >> 17], 1);
  }
  __syncthreads();
  if (tid < NPB) lofs[tid] = lhist[tid];
  __syncthreads();
  for (int off = 1; off < NPB; off <<= 1) {
    int t = 0;
    if (tid < NPB && tid >= off) t = lofs[tid - off];
    __syncthreads();
    if (tid < NPB) lofs[tid] += t;
    __syncthreads();
  }
  if (tid < NPB) {
    const int incl = lofs[tid];
    const int excl = incl - lhist[tid];
    lcur[tid] = excl;
    const int node = b * NPB + tid;
    if (node < N_NODES) {
      offs[node] = start + excl;
      ends[node] = start + incl;
    }
  }
  __syncthreads();
  for (int i = tid; i < cnt; i += ST) {
    const uint2 r = srec[i];
    const int pos = atomicAdd(&lcur[r.x >> 17], 1);
    recs[start + pos] = r;
  }
}

// ================= tier B support: exact-offset pipeline ====================

__global__ __launch_bounds__(BT) void hist2_kernel(const int* __restrict__ ei,
                                                   int* __restrict__ ghist,
                                                   const float* __restrict__ x,
                                                   unsigned short* __restrict__ xh,
                                                   int do_conv) {
  __shared__ int lh[NBUCK];
  const int tid = threadIdx.x;
  for (int i = tid; i < NBUCK; i += BT) lh[i] = 0;
  __syncthreads();
  const int cbase = blockIdx.x * CHUNK;
#pragma unroll
  for (int k = 0; k < EPT; ++k) {
    const int e = cbase + k * BT + tid;
    if (e < N_EDGES) atomicAdd(&lh[ei[N_EDGES + e] >> 7], 1);
  }
  if (do_conv) {
    const int nq = N_NODES * CH / 4;
    const int stride = gridDim.x * BT;
    for (int q = blockIdx.x * BT + tid; q < nq; q += stride) {
      const float4 v = reinterpret_cast<const float4*>(x)[q];
      ushort4 o;
      o.x = bf16rn(v.x);
      o.y = bf16rn(v.y);
      o.z = bf16rn(v.z);
      o.w = bf16rn(v.w);
      reinterpret_cast<ushort4*>(xh)[q] = o;
    }
  }
  __syncthreads();
  for (int i = tid; i < NBUCK; i += BT) {
    const int c = lh[i];
    if (c) atomicAdd(&ghist[i], c);
  }
}

__global__ __launch_bounds__(1024) void scan_kernel(const int* __restrict__ ghist,
                                                    int* __restrict__ gbase,
                                                    int* __restrict__ gcur) {
  __shared__ int sd[1024];
  const int tid = threadIdx.x;
  const int v = (tid < NBUCK) ? ghist[tid] : 0;
  sd[tid] = v;
  __syncthreads();
  for (int off = 1; off < 1024; off <<= 1) {
    int t = (tid >= off) ? sd[tid - off] : 0;
    __syncthreads();
    sd[tid] += t;
    __syncthreads();
  }
  if (tid < NBUCK) {
    const int excl = sd[tid] - v;
    gbase[tid] = excl;
    gcur[tid] = excl;
  }
}

__global__ __launch_bounds__(BT) void bin_kernel(const int* __restrict__ ei,
                                                 const float* __restrict__ attr,
                                                 const float* __restrict__ gp,
                                                 int* __restrict__ gcur,
                                                 uint2* __restrict__ recs) {
  __shared__ int lhist[NBUCK];
  __shared__ int lbase[NBUCK];
  const int tid = threadIdx.x;
  for (int i = tid; i < NBUCK; i += BT) lhist[i] = 0;
  __syncthreads();
  const int cbase = blockIdx.x * CHUNK;
  const float inv = 1.0f / (gp[0] * gp[0] + 1e-8f);

  int s[EPT], t[EPT], lrank[EPT];
  float g[EPT];
#pragma unroll
  for (int k = 0; k < EPT; ++k) {
    const int e = cbase + k * BT + tid;
    if (e < N_EDGES) {
      s[k] = ei[e];
      t[k] = ei[N_EDGES + e];
      const float d = attr[3 * e];
      g[k] = __expf(-d * d * inv);
      lrank[k] = atomicAdd(&lhist[t[k] >> 7], 1);
    }
  }
  __syncthreads();
  for (int i = tid; i < NBUCK; i += BT) {
    const int c = lhist[i];
    if (c) lbase[i] = atomicAdd(&gcur[i], c);
  }
  __syncthreads();

#pragma unroll
  for (int k = 0; k < EPT; ++k) {
    const int e = cbase + k * BT + tid;
    if (e < N_EDGES) {
      uint2 rec;
      rec.x = (unsigned)s[k] | ((unsigned)(t[k] & (NPB - 1)) << 17);
      rec.y = __float_as_uint(g[k]);
      recs[lbase[t[k] >> 7] + lrank[k]] = rec;
    }
  }
}

__global__ __launch_bounds__(ST) void sortb_kernel(const int* __restrict__ gbase,
                                                   const int* __restrict__ ghist,
                                                   uint2* __restrict__ recs,
                                                   int* __restrict__ offs) {
  __shared__ uint2 srec[CAP];  // 24 KB
  __shared__ int lhist[NPB];
  __shared__ int lofs[NPB];
  __shared__ int lcur[NPB];
  const int b = blockIdx.x;
  const int tid = threadIdx.x;
  const int start = gbase[b];
  const int cnt = ghist[b] < CAP ? ghist[b] : CAP;

  if (tid < NPB) lhist[tid] = 0;
  __syncthreads();
  for (int i = tid; i < cnt; i += ST) {
    const uint2 r = recs[start + i];
    srec[i] = r;
    atomicAdd(&lhist[r.x >> 17], 1);
  }
  __syncthreads();
  if (tid < NPB) lofs[tid] = lhist[tid];
  __syncthreads();
  for (int off = 1; off < NPB; off <<= 1) {
    int t = 0;
    if (tid < NPB && tid >= off) t = lofs[tid - off];
    __syncthreads();
    if (tid < NPB) lofs[tid] += t;
    __syncthreads();
  }
  if (tid < NPB) {
    const int excl = lofs[tid] - lhist[tid];
    lcur[tid] = excl;
    const int node = b * NPB + tid;
    if (node < N_NODES) offs[node] = start + excl;
  }
  if (b == NBUCK - 1 && tid == 0) offs[N_NODES] = start + cnt;
  __syncthreads();
  for (int i = tid; i < cnt; i += ST) {
    const uint2 r = srec[i];
    const int pos = atomicAdd(&lcur[r.x >> 17], 1);
    recs[start + pos] = r;
  }
}

// ============== shared: reduce + rowgemm ====================================

// reduce7hb (tier A+): writes agg as packed bf16 into aggh (halves WRITE).
__global__ __launch_bounds__(256) void reduce7hb_kernel(
    const unsigned short* __restrict__ xh, const int* __restrict__ offs,
    const int* __restrict__ ends, const uint2* __restrict__ recs,
    unsigned* __restrict__ aggh) {
  const int node = (blockIdx.x * blockDim.x + threadIdx.x) >> 6;
  if (node >= N_NODES) return;
  const int lane = threadIdx.x & 63;
  const int c2 = lane & 31;  // channel pair: 2*c2, 2*c2+1
  const int eh = lane >> 5;
  const int n0 = __builtin_amdgcn_readfirstlane(offs[node]);
  const int n1 = __builtin_amdgcn_readfirstlane(ends[node]);
  const int m = n1 - n0;

  float ax = 0.0f, ay = 0.0f;
  int j = 0;
  for (; j + 16 <= m; j += 16) {
#pragma unroll
    for (int p = 0; p < 8; ++p) {
      const uint2 r0 = recs[n0 + j + 2 * p];      // uniform -> s_load
      const uint2 r1 = recs[n0 + j + 2 * p + 1];
      const unsigned sx = (eh ? r1.x : r0.x) & 0x1FFFFu;
      const float g = __uint_as_float(eh ? r1.y : r0.y);
      const unsigned u =
          *reinterpret_cast<const unsigned*>(&xh[(size_t)sx * CH + c2 * 2]);
      ax += g * __uint_as_float(u << 16);
      ay += g * __uint_as_float(u & 0xFFFF0000u);
    }
  }
  for (; j + 8 <= m; j += 8) {
#pragma unroll
    for (int p = 0; p < 4; ++p) {
      const uint2 r0 = recs[n0 + j + 2 * p];
      const uint2 r1 = recs[n0 + j + 2 * p + 1];
      const unsigned sx = (eh ? r1.x : r0.x) & 0x1FFFFu;
      const float g = __uint_as_float(eh ? r1.y : r0.y);
      const unsigned u =
          *reinterpret_cast<const unsigned*>(&xh[(size_t)sx * CH + c2 * 2]);
      ax += g * __uint_as_float(u << 16);
      ay += g * __uint_as_float(u & 0xFFFF0000u);
    }
  }
  for (; j < m; j += 2) {
    const uint2 r0 = recs[n0 + j];
    uint2 r1 = {0u, 0u};
    if (j + 1 < m) r1 = recs[n0 + j + 1];
    const unsigned sx = (eh ? r1.x : r0.x) & 0x1FFFFu;
    const float g = __uint_as_float(eh ? r1.y : r0.y);
    const unsigned u =
        *reinterpret_cast<const unsigned*>(&xh[(size_t)sx * CH + c2 * 2]);
    ax += g * __uint_as_float(u << 16);
    ay += g * __uint_as_float(u & 0xFFFF0000u);
  }
  ax += __shfl_xor(ax, 32);
  ay += __shfl_xor(ay, 32);
  if (lane < 32) {
    const unsigned pk =
        ((unsigned)bf16rn(ay) << 16) | (unsigned)bf16rn(ax);
    aggh[(size_t)node * 32 + c2] = pk;
  }
}

// reduce7h (tier A/B): writes fp32 agg into out.
__global__ __launch_bounds__(256) void reduce7h_kernel(
    const unsigned short* __restrict__ xh, const int* __restrict__ offs,
    const int* __restrict__ ends, const uint2* __restrict__ recs,
    float* __restrict__ out) {
  const int node = (blockIdx.x * blockDim.x + threadIdx.x) >> 6;
  if (node >= N_NODES) return;
  const int lane = threadIdx.x & 63;
  const int c2 = lane & 31;
  const int eh = lane >> 5;
  const int n0 = __builtin_amdgcn_readfirstlane(offs[node]);
  const int n1 = __builtin_amdgcn_readfirstlane(ends[node]);
  const int m = n1 - n0;

  float ax = 0.0f, ay = 0.0f;
  int j = 0;
  for (; j + 16 <= m; j += 16) {
#pragma unroll
    for (int p = 0; p < 8; ++p) {
      const uint2 r0 = recs[n0 + j + 2 * p];
      const uint2 r1 = recs[n0 + j + 2 * p + 1];
      const unsigned sx = (eh ? r1.x : r0.x) & 0x1FFFFu;
      const float g = __uint_as_float(eh ? r1.y : r0.y);
      const unsigned u =
          *reinterpret_cast<const unsigned*>(&xh[(size_t)sx * CH + c2 * 2]);
      ax += g * __uint_as_float(u << 16);
      ay += g * __uint_as_float(u & 0xFFFF0000u);
    }
  }
  for (; j + 8 <= m; j += 8) {
#pragma unroll
    for (int p = 0; p < 4; ++p) {
      const uint2 r0 = recs[n0 + j + 2 * p];
      const uint2 r1 = recs[n0 + j + 2 * p + 1];
      const unsigned sx = (eh ? r1.x : r0.x) & 0x1FFFFu;
      const float g = __uint_as_float(eh ? r1.y : r0.y);
      const unsigned u =
          *reinterpret_cast<const unsigned*>(&xh[(size_t)sx * CH + c2 * 2]);
      ax += g * __uint_as_float(u << 16);
      ay += g * __uint_as_float(u & 0xFFFF0000u);
    }
  }
  for (; j < m; j += 2) {
    const uint2 r0 = recs[n0 + j];
    uint2 r1 = {0u, 0u};
    if (j + 1 < m) r1 = recs[n0 + j + 1];
    const unsigned sx = (eh ? r1.x : r0.x) & 0x1FFFFu;
    const float g = __uint_as_float(eh ? r1.y : r0.y);
    const unsigned u =
        *reinterpret_cast<const unsigned*>(&xh[(size_t)sx * CH + c2 * 2]);
    ax += g * __uint_as_float(u << 16);
    ay += g * __uint_as_float(u & 0xFFFF0000u);
  }
  ax += __shfl_xor(ax, 32);
  ay += __shfl_xor(ay, 32);
  if (lane < 32) {
    float2 o;
    o.x = ax;
    o.y = ay;
    reinterpret_cast<float2*>(out + (size_t)node * CH)[c2] = o;
  }
}

// reduce3 (tier C): fp32 gathers via shfl broadcast; writes s = agg + x.
__global__ __launch_bounds__(256) void reduce3_kernel(
    const float* __restrict__ x, const int* __restrict__ offs,
    const uint2* __restrict__ recs, float* __restrict__ out) {
  const int node = (blockIdx.x * blockDim.x + threadIdx.x) >> 6;
  if (node >= N_NODES) return;
  const int lane = threadIdx.x & 63;
  const int n0 = offs[node];
  const int m = offs[node + 1] - n0;

  float acc = 0.0f;
  for (int base = 0; base < m; base += 64) {
    const int mm = (m - base) < 64 ? (m - base) : 64;
    uint2 pr = {0u, 0u};
    if (lane < mm) pr = recs[n0 + base + lane];
    const int pk_all = (int)pr.x;
    const float g_all = __uint_as_float(pr.y);
    int j = 0;
    for (; j + 4 <= mm; j += 4) {
      const int s0 = __shfl(pk_all, j + 0) & 0x1FFFF;
      const int s1 = __shfl(pk_all, j + 1) & 0x1FFFF;
      const int s2 = __shfl(pk_all, j + 2) & 0x1FFFF;
      const int s3 = __shfl(pk_all, j + 3) & 0x1FFFF;
      const float g0 = __shfl(g_all, j + 0);
      const float g1 = __shfl(g_all, j + 1);
      const float g2 = __shfl(g_all, j + 2);
      const float g3 = __shfl(g_all, j + 3);
      acc += g0 * x[(size_t)s0 * CH + lane] + g1 * x[(size_t)s1 * CH + lane] +
             g2 * x[(size_t)s2 * CH + lane] + g3 * x[(size_t)s3 * CH + lane];
    }
    for (; j < mm; ++j) {
      const int sj = __shfl(pk_all, j) & 0x1FFFF;
      const float gj = __shfl(g_all, j);
      acc += gj * x[(size_t)sj * CH + lane];
    }
  }
  out[(size_t)node * CH + lane] = acc + x[(size_t)node * CH + lane];
}

// fallback: atomic scatter
__global__ __launch_bounds__(256) void scatter_kernel(
    const float* __restrict__ x, const int* __restrict__ ei,
    const float* __restrict__ attr, const float* __restrict__ gp,
    float* __restrict__ agg) {
  const int lane = threadIdx.x & 63;
  const int wave = (blockIdx.x * blockDim.x + threadIdx.x) >> 6;
  const int nwaves = (gridDim.x * blockDim.x) >> 6;
  const float inv = 1.0f / (gp[0] * gp[0] + 1e-8f);
  for (int base = wave * 64; base < N_EDGES; base += nwaves * 64) {
    const int e = base + lane;
    const int s = ei[e];
    const int t = ei[N_EDGES + e];
    const float d = attr[3 * e];
    const float g = __expf(-d * d * inv);
#pragma unroll 1
    for (int j = 0; j < 64; ++j) {
      const int sj = __shfl(s, j);
      const int tj = __shfl(t, j);
      const float gj = __shfl(g, j);
      atomicAdd(&agg[(size_t)tj * CH + lane], gj * x[sj * CH + lane]);
    }
  }
}

// rowgemm5 (tier A+): out = (bf16 aggh + x) @ W + bias.
__global__ __launch_bounds__(256) void rowgemm5_kernel(
    const unsigned short* __restrict__ aggh, const float* __restrict__ x,
    const float* __restrict__ W, const float* __restrict__ bias,
    float* __restrict__ out) {
  __shared__ float sT[64][GM + 4];
  __shared__ float wl[64 * 64];
  const int tid = threadIdx.x;
  const int node0 = blockIdx.x * GM;

  {
    const float4* W4 = reinterpret_cast<const float4*>(W);
    float4* wl4 = reinterpret_cast<float4*>(wl);
#pragma unroll
    for (int i = 0; i < 4; ++i) wl4[i * 256 + tid] = W4[i * 256 + tid];
  }
  {
    const int m = tid >> 2;
    const int kq = tid & 3;
    if (node0 + m < N_NODES) {
      const float4* x4 =
          reinterpret_cast<const float4*>(x + (size_t)(node0 + m) * CH);
      const uint2* a2 = reinterpret_cast<const uint2*>(
          aggh + (size_t)(node0 + m) * CH + kq * 16);
#pragma unroll
      for (int q = 0; q < 4; ++q) {
        const uint2 hv = a2[q];
        const float4 xv = x4[kq * 4 + q];
        const int k = kq * 16 + q * 4;
        sT[k + 0][m] = bf16f((unsigned short)(hv.x & 0xFFFF)) + xv.x;
        sT[k + 1][m] = bf16f((unsigned short)(hv.x >> 16)) + xv.y;
        sT[k + 2][m] = bf16f((unsigned short)(hv.y & 0xFFFF)) + xv.z;
        sT[k + 3][m] = bf16f((unsigned short)(hv.y >> 16)) + xv.w;
      }
    }
  }
  __syncthreads();

  const int m0 = (tid >> 4) * 4;
  const int c0 = (tid & 15) * 4;

  const f32x4 b4 = *reinterpret_cast<const f32x4*>(&bias[c0]);
  f32x4 acc0 = b4, acc1 = b4, acc2 = b4, acc3 = b4;

#pragma unroll 8
  for (int k = 0; k < 64; ++k) {
    const f32x4 sv = *reinterpret_cast<const f32x4*>(&sT[k][m0]);
    const f32x4 wv = *reinterpret_cast<const f32x4*>(&wl[k * 64 + c0]);
    acc0 += sv.x * wv;
    acc1 += sv.y * wv;
    acc2 += sv.z * wv;
    acc3 += sv.w * wv;
  }

  __syncthreads();
  f32x4 accs[4] = {acc0, acc1, acc2, acc3};
#pragma unroll
  for (int i = 0; i < 4; ++i) {
    const int node = node0 + m0 + i;
    if (node < N_NODES)
      *reinterpret_cast<f32x4*>(&out[(size_t)node * CH + c0]) = accs[i];
  }
}

// rowgemm4 (tiers A/B): out = (out + x) @ W + bias, in place.
__global__ __launch_bounds__(256) void rowgemm4_kernel(
    const float* __restrict__ x, const float* __restrict__ W,
    const float* __restrict__ bias, float* __restrict__ out) {
  __shared__ float sT[64][GM + 4];
  __shared__ float wl[64 * 64];
  const int tid = threadIdx.x;
  const int node0 = blockIdx.x * GM;

  {
    const float4* W4 = reinterpret_cast<const float4*>(W);
    float4* wl4 = reinterpret_cast<float4*>(wl);
#pragma unroll
    for (int i = 0; i < 4; ++i) wl4[i * 256 + tid] = W4[i * 256 + tid];
  }
  {
    const int m = tid >> 2;
    const int kq = tid & 3;
    if (node0 + m < N_NODES) {
      const float4* r4 =
          reinterpret_cast<const float4*>(out + (size_t)(node0 + m) * CH);
      const float4* x4 =
          reinterpret_cast<const float4*>(x + (size_t)(node0 + m) * CH);
#pragma unroll
      for (int q = 0; q < 4; ++q) {
        const float4 v = r4[kq * 4 + q];
        const float4 xv = x4[kq * 4 + q];
        const int k = kq * 16 + q * 4;
        sT[k + 0][m] = v.x + xv.x;
        sT[k + 1][m] = v.y + xv.y;
        sT[k + 2][m] = v.z + xv.z;
        sT[k + 3][m] = v.w + xv.w;
      }
    }
  }
  __syncthreads();

  const int m0 = (tid >> 4) * 4;
  const int c0 = (tid & 15) * 4;

  const f32x4 b4 = *reinterpret_cast<const f32x4*>(&bias[c0]);
  f32x4 acc0 = b4, acc1 = b4, acc2 = b4, acc3 = b4;

#pragma unroll 8
  for (int k = 0; k < 64; ++k) {
    const f32x4 sv = *reinterpret_cast<const f32x4*>(&sT[k][m0]);
    const f32x4 wv = *reinterpret_cast<const f32x4*>(&wl[k * 64 + c0]);
    acc0 += sv.x * wv;
    acc1 += sv.y * wv;
    acc2 += sv.z * wv;
    acc3 += sv.w * wv;
  }

  __syncthreads();
  f32x4 accs[4] = {acc0, acc1, acc2, acc3};
#pragma unroll
  for (int i = 0; i < 4; ++i) {
    const int node = node0 + m0 + i;
    if (node < N_NODES)
      *reinterpret_cast<f32x4*>(&out[(size_t)node * CH + c0]) = accs[i];
  }
}

// rowgemm3 (tier C): out = out @ W + bias (s already includes x).
__global__ __launch_bounds__(256) void rowgemm3_kernel(
    const float* __restrict__ W, const float* __restrict__ bias,
    float* __restrict__ out) {
  __shared__ float sT[64][GM + 4];
  __shared__ float wl[64 * 64];
  const int tid = threadIdx.x;
  const int node0 = blockIdx.x * GM;

  {
    const float4* W4 = reinterpret_cast<const float4*>(W);
    float4* wl4 = reinterpret_cast<float4*>(wl);
#pragma unroll
    for (int i = 0; i < 4; ++i) wl4[i * 256 + tid] = W4[i * 256 + tid];
  }
  {
    const int m = tid >> 2;
    const int kq = tid & 3;
    if (node0 + m < N_NODES) {
      const float4* r4 =
          reinterpret_cast<const float4*>(out + (size_t)(node0 + m) * CH);
#pragma unroll
      for (int q = 0; q < 4; ++q) {
        const float4 v = r4[kq * 4 + q];
        const int k = kq * 16 + q * 4;
        sT[k + 0][m] = v.x;
        sT[k + 1][m] = v.y;
        sT[k + 2][m] = v.z;
        sT[k + 3][m] = v.w;
      }
    }
  }
  __syncthreads();

  const int m0 = (tid >> 4) * 4;
  const int c0 = (tid & 15) * 4;

  const f32x4 b4 = *reinterpret_cast<const f32x4*>(&bias[c0]);
  f32x4 acc0 = b4, acc1 = b4, acc2 = b4, acc3 = b4;

#pragma unroll 8
  for (int k = 0; k < 64; ++k) {
    const f32x4 sv = *reinterpret_cast<const f32x4*>(&sT[k][m0]);
    const f32x4 wv = *reinterpret_cast<const f32x4*>(&wl[k * 64 + c0]);
    acc0 += sv.x * wv;
    acc1 += sv.y * wv;
    acc2 += sv.z * wv;
    acc3 += sv.w * wv;
  }

  __syncthreads();
  f32x4 accs[4] = {acc0, acc1, acc2, acc3};
#pragma unroll
  for (int i = 0; i < 4; ++i) {
    const int node = node0 + m0 + i;
    if (node < N_NODES)
      *reinterpret_cast<f32x4*>(&out[(size_t)node * CH + c0]) = accs[i];
  }
}

// rowgemm (tier D): out = (x + out) @ W + bias.
__global__ __launch_bounds__(256) void rowgemm_kernel(
    const float* __restrict__ x, const float* __restrict__ W,
    const float* __restrict__ bias, float* __restrict__ out) {
  const int r = blockIdx.x * blockDim.x + threadIdx.x;
  if (r >= N_NODES) return;
  const float* xr = x + (size_t)r * CH;
  float* outr = out + (size_t)r * CH;

  float s[CH];
#pragma unroll
  for (int k4 = 0; k4 < CH / 4; ++k4) {
    float4 xv = *reinterpret_cast<const float4*>(xr + k4 * 4);
    float4 av = *reinterpret_cast<const float4*>(outr + k4 * 4);
    s[k4 * 4 + 0] = xv.x + av.x;
    s[k4 * 4 + 1] = xv.y + av.y;
    s[k4 * 4 + 2] = xv.z + av.z;
    s[k4 * 4 + 3] = xv.w + av.w;
  }

  float acc[CH];
#pragma unroll
  for (int c = 0; c < CH; ++c) acc[c] = bias[c];

#pragma unroll
  for (int k = 0; k < CH; ++k) {
    const float sk = s[k];
#pragma unroll
    for (int c4 = 0; c4 < CH / 4; ++c4) {
      const float4 w = *reinterpret_cast<const float4*>(&W[k * CH + c4 * 4]);
      acc[c4 * 4 + 0] += sk * w.x;
      acc[c4 * 4 + 1] += sk * w.y;
      acc[c4 * 4 + 2] += sk * w.z;
      acc[c4 * 4 + 3] += sk * w.w;
    }
  }

#pragma unroll
  for (int c4 = 0; c4 < CH / 4; ++c4) {
    float4 o = {acc[c4 * 4 + 0], acc[c4 * 4 + 1], acc[c4 * 4 + 2],
                acc[c4 * 4 + 3]};
    *reinterpret_cast<float4*>(outr + c4 * 4) = o;
  }
}

// ---------- launch ----------
extern "C" void kernel_launch(void* const* d_in, const int* in_sizes, int n_in,
                              void* d_out, int out_size, void* d_ws,
                              size_t ws_size, hipStream_t stream) {
  const float* x = (const float*)d_in[0];
  const int* ei = (const int*)d_in[1];  // harness delivers int32
  const float* attr = (const float*)d_in[2];
  const float* W = (const float*)d_in[3];
  const float* bias = (const float*)d_in[4];
  const float* gp = (const float*)d_in[5];
  float* out = (float*)d_out;

  const size_t sz_i = ((size_t)NBUCK * 4 + 255) & ~(size_t)255;  // 3328
  const size_t sz_xh = (size_t)N_NODES * CH * 2;                 // 12.8 MB
  const size_t sz_offs1 = ((size_t)N_NODES * 4 + 255) & ~(size_t)255;
  const size_t sz_aggh = ((size_t)N_NODES * CH * 2 + 255) & ~(size_t)255;

  // Tier A (fixed stride): gcur | recsA | offs | ends | xh [| aggh: tier A+]
  const size_t sz_recsA = (size_t)NBUCK * STRIDE * 8;  // 16.0 MB
  const size_t need_fs = sz_i + sz_recsA + 2 * sz_offs1 + sz_xh;   // ~29.6 MB
  const size_t need_fs2 = need_fs + sz_aggh;                       // ~42.4 MB

  // Tier B/C (exact offsets): ghist|gbase|gcur | recs (12.8MB) | offs(N+1) | xh
  const size_t sz_recsB = (size_t)N_EDGES * 8;
  const size_t sz_offsB = ((size_t)(N_NODES + 1) * 4 + 255) & ~(size_t)255;
  const size_t need_b = 3 * sz_i + sz_recsB + sz_offsB;  // ~13.2 MB
  const size_t need_a = need_b + sz_xh;                  // ~26.0 MB

  if (ws_size >= need_fs) {
    char* base = (char*)d_ws;
    int* gcur = (int*)base;
    uint2* recs = (uint2*)(base + sz_i);
    int* offs = (int*)(base + sz_i + sz_recsA);
    int* ends = (int*)(base + sz_i + sz_recsA + sz_offs1);
    unsigned short* xh =
        (unsigned short*)(base + sz_i + sz_recsA + 2 * sz_offs1);
    unsigned short* aggh = (unsigned short*)(base + need_fs);

    hipMemsetAsync(gcur, 0, (size_t)NBUCK * 4, stream);
    bin2_kernel<<<NBLK_E, BT, 0, stream>>>(ei, attr, gp, gcur, recs, x, xh);
    sortb2_kernel<<<NBUCK, ST, 0, stream>>>(gcur, recs, offs, ends);
    if (ws_size >= need_fs2) {
      reduce7hb_kernel<<<(N_NODES * 64 + 255) / 256, 256, 0, stream>>>(
          xh, offs, ends, recs, (unsigned*)aggh);
      rowgemm5_kernel<<<(N_NODES + GM - 1) / GM, 256, 0, stream>>>(
          aggh, x, W, bias, out);
    } else {
      reduce7h_kernel<<<(N_NODES * 64 + 255) / 256, 256, 0, stream>>>(
          xh, offs, ends, recs, out);
      rowgemm4_kernel<<<(N_NODES + GM - 1) / GM, 256, 0, stream>>>(x, W, bias,
                                                                   out);
    }
  } else if (ws_size >= need_b) {
    char* base = (char*)d_ws;
    int* ghist = (int*)base;
    int* gbase = (int*)(base + sz_i);
    int* gcur = (int*)(base + 2 * sz_i);
    uint2* recs = (uint2*)(base + 3 * sz_i);
    int* offs = (int*)(base + 3 * sz_i + sz_recsB);
    unsigned short* xh = (unsigned short*)(base + need_b);

    const int tier_a = (ws_size >= need_a) ? 1 : 0;
    hipMemsetAsync(ghist, 0, (size_t)NBUCK * 4, stream);
    hist2_kernel<<<NBLK_E, BT, 0, stream>>>(ei, ghist, x, xh, tier_a);
    scan_kernel<<<1, 1024, 0, stream>>>(ghist, gbase, gcur);
    bin_kernel<<<NBLK_E, BT, 0, stream>>>(ei, attr, gp, gcur, recs);
    sortb_kernel<<<NBUCK, ST, 0, stream>>>(gbase, ghist, recs, offs);
    if (tier_a) {
      reduce7h_kernel<<<(N_NODES * 64 + 255) / 256, 256, 0, stream>>>(
          xh, offs, offs + 1, recs, out);
      rowgemm4_kernel<<<(N_NODES + GM - 1) / GM, 256, 0, stream>>>(x, W, bias,
                                                                   out);
    } else {
      reduce3_kernel<<<(N_NODES * 64 + 255) / 256, 256, 0, stream>>>(x, offs,
                                                                     recs, out);
      rowgemm3_kernel<<<(N_NODES + GM - 1) / GM, 256, 0, stream>>>(W, bias,
                                                                   out);
    }
  } else {
    hipMemsetAsync(out, 0, (size_t)N_NODES * CH * sizeof(float), stream);
    scatter_kernel<<<2048, 256, 0, stream>>>(x, ei, attr, gp, out);
    rowgemm_kernel<<<(N_NODES + 255) / 256, 256, 0, stream>>>(x, W, bias, out);
  }
}